// Round 1
// baseline (198.048 us; speedup 1.0000x reference)
//
#include <hip/hip_runtime.h>

// ---------------------------------------------------------------------------
// DigitConvolutionalModel: x(32768,784) -> conv3x3(valid) -> 676
//   -> relu(@W1(676,300)+b1) -> relu(@W2(300,300)+b2) -> @W3(300,10)+b3
//
// Strategy:
//  - conv folded into W1: W1eff(784,300). Prep kernel builds bf16 weights in
//    MFMA B-frag order (16x16x32 bf16), zero-padded: K1=800(25 chunks of 32),
//    K2=K3=320(10 chunks), N=320(20 tiles of 16), N3=16(1 tile).
//  - main kernel: 512 blocks x 64 rows, 256 thr (4 waves), waves split N
//    (5 n-tiles each). x staged fp32->bf16 via LDS (A-frag order), weights
//    read as B-frags directly from global (L2-resident). h1/h2 stay in LDS.
// ---------------------------------------------------------------------------

typedef __bf16 bf16_t;
typedef __bf16 bf16x8 __attribute__((ext_vector_type(8)));
typedef float  f32x4  __attribute__((ext_vector_type(4)));

#define MFMA16(a, b, c) __builtin_amdgcn_mfma_f32_16x16x32_bf16((a), (b), (c), 0, 0, 0)

// fragment-order element counts
#define W1F_ELEMS (25 * 20 * 64 * 8)  // 256000  (K=800, N=320)
#define W2F_ELEMS (10 * 20 * 64 * 8)  // 102400  (K=320, N=320)
#define W3F_ELEMS (10 * 1 * 64 * 8)   // 5120    (K=320, N=16)

// ---------------------------------------------------------------------------
// Prep: build bf16 weight buffers in MFMA B-fragment order.
// frag addr for (k, n): kc=k>>5, quad=(k&31)>>3, j=k&7, nt=n>>4, nin=n&15
//   elem = ((kc*NT + nt)*64 + quad*16 + nin)*8 + j
// ---------------------------------------------------------------------------
__global__ void prep_weights(const float* __restrict__ conv_w,
                             const float* __restrict__ W1,
                             const float* __restrict__ W2,
                             const float* __restrict__ W3,
                             bf16_t* __restrict__ W1f,
                             bf16_t* __restrict__ W2f,
                             bf16_t* __restrict__ W3f) {
    int idx = blockIdx.x * 256 + threadIdx.x;
    if (idx < 800 * 320) {
        // W1eff[p=k][n] = sum_{ky,kx} conv_w[ky,kx] * W1[(py-ky)*26+(px-kx)][n]
        int k = idx / 320;
        int n = idx - k * 320;
        float v = 0.0f;
        if (k < 784 && n < 300) {
            int py = k / 28;
            int px = k - py * 28;
#pragma unroll
            for (int ky = 0; ky < 3; ++ky) {
                int oy = py - ky;
                if (oy < 0 || oy > 25) continue;
#pragma unroll
                for (int kx = 0; kx < 3; ++kx) {
                    int ox = px - kx;
                    if (ox < 0 || ox > 25) continue;
                    v += conv_w[ky * 3 + kx] * W1[(oy * 26 + ox) * 300 + n];
                }
            }
        }
        int kc = k >> 5, quad = (k >> 3) & 3, j = k & 7;
        int nt = n >> 4, nin = n & 15;
        W1f[(((kc * 20 + nt) * 64 + quad * 16 + nin) << 3) + j] = (bf16_t)v;
    } else if (idx < 800 * 320 + 320 * 320) {
        int i2 = idx - 800 * 320;
        int k = i2 / 320;
        int n = i2 - k * 320;
        float v = (k < 300 && n < 300) ? W2[k * 300 + n] : 0.0f;
        int kc = k >> 5, quad = (k >> 3) & 3, j = k & 7;
        int nt = n >> 4, nin = n & 15;
        W2f[(((kc * 20 + nt) * 64 + quad * 16 + nin) << 3) + j] = (bf16_t)v;
    } else if (idx < 800 * 320 + 320 * 320 + 320 * 16) {
        int i3 = idx - (800 * 320 + 320 * 320);
        int k = i3 / 16;
        int n = i3 - k * 16;
        float v = (k < 300 && n < 10) ? W3[k * 10 + n] : 0.0f;
        int kc = k >> 5, quad = (k >> 3) & 3, j = k & 7;
        W3f[(((kc * 64) + quad * 16 + n) << 3) + j] = (bf16_t)v;
    }
}

// ---------------------------------------------------------------------------
// Fused 3-layer MLP. 64 rows/block, 256 threads = 4 waves.
// Wave w owns n-tiles [w*5, w*5+5) of the 20-tile (N=320) output.
// A-frag (16x16x32 bf16): A[m=lane&15][k=(lane>>4)*8+j]
// C/D:                    col=lane&15, row=(lane>>4)*4+reg
// ---------------------------------------------------------------------------
__global__ __launch_bounds__(256, 2) void fused_mlp(
    const float* __restrict__ x, const float* __restrict__ b1,
    const float* __restrict__ b2, const float* __restrict__ b3,
    const bf16x8* __restrict__ W1f, const bf16x8* __restrict__ W2f,
    const bf16x8* __restrict__ W3f, float* __restrict__ out) {
    __shared__ bf16x8 bufA[4 * 64];       // 4 KB: one 64x32 A chunk (frag order)
    __shared__ bf16x8 hbuf[10 * 4 * 64];  // 40 KB: 64x320 h in A-frag order

    const int tid = threadIdx.x;
    const int w = tid >> 6;    // wave 0..3
    const int l = tid & 63;    // lane
    const int r0 = blockIdx.x * 64;

    // staging assignment: thread -> (row sr, k-octet sg)
    const int sr = tid >> 2;                  // 0..63
    const int sg = tid & 3;                   // 0..3 (8 k-values each)
    const int s_mt = sr >> 4;                 // m-tile of staged row
    const int s_lane = sg * 16 + (sr & 15);   // frag lane position
    const float* xrow = x + (size_t)(r0 + sr) * 784;

    f32x4 acc[4][5];
#pragma unroll
    for (int mt = 0; mt < 4; ++mt)
#pragma unroll
        for (int nt = 0; nt < 5; ++nt) acc[mt][nt] = (f32x4){0.f, 0.f, 0.f, 0.f};

    // ---------------- GEMM1: (64x800) @ W1eff(800x320), 25 k-chunks --------
    float4 u0, u1;
    {
        int k0 = sg * 8;  // chunk 0
        const float4* p = (const float4*)(xrow + k0);
        u0 = p[0];
        u1 = p[1];
    }
    for (int kc = 0; kc < 25; ++kc) {
        bf16x8 af;
        af[0] = (bf16_t)u0.x; af[1] = (bf16_t)u0.y;
        af[2] = (bf16_t)u0.z; af[3] = (bf16_t)u0.w;
        af[4] = (bf16_t)u1.x; af[5] = (bf16_t)u1.y;
        af[6] = (bf16_t)u1.z; af[7] = (bf16_t)u1.w;
        bufA[s_mt * 64 + s_lane] = af;
        __syncthreads();
        // prefetch next chunk while computing this one
        if (kc + 1 < 25) {
            int k0 = (kc + 1) * 32 + sg * 8;
            if (k0 < 784) {
                const float4* p = (const float4*)(xrow + k0);
                u0 = p[0];
                u1 = p[1];
            } else {
                u0 = make_float4(0.f, 0.f, 0.f, 0.f);
                u1 = make_float4(0.f, 0.f, 0.f, 0.f);
            }
        }
        bf16x8 a0 = bufA[0 * 64 + l];
        bf16x8 a1 = bufA[1 * 64 + l];
        bf16x8 a2 = bufA[2 * 64 + l];
        bf16x8 a3 = bufA[3 * 64 + l];
        const bf16x8* wb = W1f + (size_t)(kc * 20 + w * 5) * 64 + l;
#pragma unroll
        for (int nt = 0; nt < 5; ++nt) {
            bf16x8 b = wb[nt * 64];
            acc[0][nt] = MFMA16(a0, b, acc[0][nt]);
            acc[1][nt] = MFMA16(a1, b, acc[1][nt]);
            acc[2][nt] = MFMA16(a2, b, acc[2][nt]);
            acc[3][nt] = MFMA16(a3, b, acc[3][nt]);
        }
        __syncthreads();
    }

    // ---------------- h1 = relu(C1 + b1) -> LDS (A-frag order) -------------
    {
        bf16_t* hb = (bf16_t*)hbuf;
#pragma unroll
        for (int nt = 0; nt < 5; ++nt) {
            int n = (w * 5 + nt) * 16 + (l & 15);
            float bias = (n < 300) ? b1[n] : 0.0f;
            int kc2 = n >> 5, quad = (n >> 3) & 3, j = n & 7;
#pragma unroll
            for (int mt = 0; mt < 4; ++mt) {
#pragma unroll
                for (int r = 0; r < 4; ++r) {
                    int row15 = (l >> 4) * 4 + r;
                    float v = acc[mt][nt][r] + bias;
                    v = v > 0.f ? v : 0.f;
                    hb[(((kc2 * 4 + mt) * 64 + quad * 16 + row15) << 3) + j] = (bf16_t)v;
                }
            }
        }
    }
    __syncthreads();

    // ---------------- GEMM2: (64x320) @ W2(320x320), 10 k-chunks -----------
#pragma unroll
    for (int mt = 0; mt < 4; ++mt)
#pragma unroll
        for (int nt = 0; nt < 5; ++nt) acc[mt][nt] = (f32x4){0.f, 0.f, 0.f, 0.f};
    for (int kc = 0; kc < 10; ++kc) {
        bf16x8 a0 = hbuf[(kc * 4 + 0) * 64 + l];
        bf16x8 a1 = hbuf[(kc * 4 + 1) * 64 + l];
        bf16x8 a2 = hbuf[(kc * 4 + 2) * 64 + l];
        bf16x8 a3 = hbuf[(kc * 4 + 3) * 64 + l];
        const bf16x8* wb = W2f + (size_t)(kc * 20 + w * 5) * 64 + l;
#pragma unroll
        for (int nt = 0; nt < 5; ++nt) {
            bf16x8 b = wb[nt * 64];
            acc[0][nt] = MFMA16(a0, b, acc[0][nt]);
            acc[1][nt] = MFMA16(a1, b, acc[1][nt]);
            acc[2][nt] = MFMA16(a2, b, acc[2][nt]);
            acc[3][nt] = MFMA16(a3, b, acc[3][nt]);
        }
    }
    __syncthreads();  // all waves done reading h1 before overwrite

    // ---------------- h2 = relu(C2 + b2) -> LDS (A-frag order) -------------
    {
        bf16_t* hb = (bf16_t*)hbuf;
#pragma unroll
        for (int nt = 0; nt < 5; ++nt) {
            int n = (w * 5 + nt) * 16 + (l & 15);
            float bias = (n < 300) ? b2[n] : 0.0f;
            int kc2 = n >> 5, quad = (n >> 3) & 3, j = n & 7;
#pragma unroll
            for (int mt = 0; mt < 4; ++mt) {
#pragma unroll
                for (int r = 0; r < 4; ++r) {
                    int row15 = (l >> 4) * 4 + r;
                    float v = acc[mt][nt][r] + bias;
                    v = v > 0.f ? v : 0.f;
                    hb[(((kc2 * 4 + mt) * 64 + quad * 16 + row15) << 3) + j] = (bf16_t)v;
                }
            }
        }
    }
    __syncthreads();

    // ---------------- GEMM3: (64x320) @ W3(320x16); wave w -> m-tile w -----
    f32x4 acc3 = (f32x4){0.f, 0.f, 0.f, 0.f};
    for (int kc = 0; kc < 10; ++kc) {
        bf16x8 a = hbuf[(kc * 4 + w) * 64 + l];
        bf16x8 b = W3f[kc * 64 + l];
        acc3 = MFMA16(a, b, acc3);
    }
    int n = l & 15;
    if (n < 10) {
        float bias = b3[n];
#pragma unroll
        for (int r = 0; r < 4; ++r) {
            int row = r0 + w * 16 + (l >> 4) * 4 + r;
            out[row * 10 + n] = acc3[r] + bias;
        }
    }
}

// ---------------------------------------------------------------------------
extern "C" void kernel_launch(void* const* d_in, const int* in_sizes, int n_in,
                              void* d_out, int out_size, void* d_ws, size_t ws_size,
                              hipStream_t stream) {
    const float* x      = (const float*)d_in[0];
    const float* conv_w = (const float*)d_in[1];
    const float* W1     = (const float*)d_in[2];
    const float* b1     = (const float*)d_in[3];
    const float* W2     = (const float*)d_in[4];
    const float* b2     = (const float*)d_in[5];
    const float* W3     = (const float*)d_in[6];
    const float* b3     = (const float*)d_in[7];
    float* out = (float*)d_out;

    char* ws = (char*)d_ws;
    bf16_t* W1f = (bf16_t*)(ws);
    bf16_t* W2f = (bf16_t*)(ws + (size_t)W1F_ELEMS * 2);
    bf16_t* W3f = (bf16_t*)(ws + (size_t)(W1F_ELEMS + W2F_ELEMS) * 2);
    if (ws_size < (size_t)(W1F_ELEMS + W2F_ELEMS + W3F_ELEMS) * 2) return;

    int prep_total = 800 * 320 + 320 * 320 + 320 * 16;  // 363520
    prep_weights<<<(prep_total + 255) / 256, 256, 0, stream>>>(
        conv_w, W1, W2, W3, W1f, W2f, W3f);

    fused_mlp<<<32768 / 64, 256, 0, stream>>>(
        x, b1, b2, b3, (const bf16x8*)W1f, (const bf16x8*)W2f,
        (const bf16x8*)W3f, out);
}